// Round 8
// baseline (653.512 us; speedup 1.0000x reference)
//
#include <hip/hip_runtime.h>
#include <hip/hip_fp16.h>
#include <math.h>

#define T_LEN   720
#define V_DIM   64
#define KBINS   4
#define NKNOTS  4
#define BLOCK   512     // 8 waves; launch_bounds(512,8) -> 4 blocks/CU = 32 waves

// ws float offsets (kernel A -> kernel B)
#define WS_TAB  0       // [720][8] = {cos k0..3, sin k0..3} per t (f32 in ws)
#define WS_SR   5760    // [4][64]  Re(scale)-1, [k][v]
#define WS_SI   6016    // [4][64]  Im(scale),   [k][v]
#define WS_KN   6272    // [4][64]  clipped knots, [n][v]
#define WS_END  6528

// ---- Kernel A: one-time tables (no transcendentals in kernel B) ----
__global__ __launch_bounds__(256) void precompute_kernel(
    const float* __restrict__ a, const float* __restrict__ phi,
    const float* __restrict__ env_knots, const int* __restrict__ k_bins,
    float* __restrict__ ws)
{
    int id = blockIdx.x * 256 + threadIdx.x;
    if (id < T_LEN * KBINS) {
        int t = id >> 2, k = id & 3;
        int kb = k_bins[k];
        int m  = (kb * t) % T_LEN;                       // exact integer angle reduction
        float th = (float)m * 0.00872664625997164788f;   // 2*pi/720
        float sn, cs;
        sincosf(th, &sn, &cs);
        ws[WS_TAB + t * 8 + k]     = cs;
        ws[WS_TAB + t * 8 + 4 + k] = sn;
    } else if (id < T_LEN * KBINS + V_DIM * KBINS) {
        int e = id - T_LEN * KBINS;                      // v*4+k
        int v = e >> 2, k = e & 3;
        float amp = 1.0f + a[e];
        float ph  = tanhf(phi[e]) * 0.25f;
        float sp, cp;
        sincosf(ph, &sp, &cp);
        ws[WS_SR + k * V_DIM + v] = amp * cp - 1.0f;
        ws[WS_SI + k * V_DIM + v] = amp * sp;
    } else if (id < T_LEN * KBINS + V_DIM * KBINS + V_DIM * NKNOTS) {
        int e = id - T_LEN * KBINS - V_DIM * KBINS;      // v*4+n
        int v = e >> 2, n = e & 3;
        ws[WS_KN + n * V_DIM + v] = fminf(fmaxf(env_knots[e], 0.5f), 1.5f);
    }
}

// ---- Kernel B: one block per b; deterministic reduce; fp16 trig in LDS ----
// LDS 33.6 KB -> 4 blocks/CU; VGPR capped 64 -> 32 waves/CU (100%).
__global__ __launch_bounds__(BLOCK, 8) void SeasonalEnvelopeAdapter_kernel(
    const float* __restrict__ y,
    const float* __restrict__ ws,
    float* __restrict__ out)
{
    __shared__ __align__(16) __half tabh[T_LEN][8];      // 11,520 B {c0..3,s0..3}/t
    __shared__ float red[16][9][33];                     // 19,008 B (writer lanes: 16 distinct banks)
    __shared__ __align__(16) float coefT[8][V_DIM];      //  2,048 B [k][v] re / [4+k][v] im
    __shared__ __align__(16) float knT[NKNOTS][V_DIM];   //  1,024 B
    // total 33,600 B

    const int tid  = threadIdx.x;
    const int b    = blockIdx.x;
    const int g    = tid & 15;      // v-group: v0 = 4*g -> 256 B/row coalesced
    const int s    = tid >> 4;      // t-phase 0..31 (t = s + 32*i)
    const int lane = tid & 63;
    const int w    = tid >> 6;      // wave 0..7
    const int niter = (s < 16) ? 23 : 22;   // 720 = 32*22 + 16, wave-uniform

    // ---- Phase 0: ws tables -> LDS (trig converted to fp16) ----
    for (int t = tid; t < T_LEN; t += BLOCK) {
        float4 c4 = *(const float4*)(ws + WS_TAB + t * 8);
        float4 s4 = *(const float4*)(ws + WS_TAB + t * 8 + 4);
        __half h[8];
        h[0] = __float2half_rn(c4.x); h[1] = __float2half_rn(c4.y);
        h[2] = __float2half_rn(c4.z); h[3] = __float2half_rn(c4.w);
        h[4] = __float2half_rn(s4.x); h[5] = __float2half_rn(s4.y);
        h[6] = __float2half_rn(s4.z); h[7] = __float2half_rn(s4.w);
        *(uint4*)(&tabh[t][0]) = *(const uint4*)(&h[0]);
    }
    if (tid < NKNOTS * V_DIM) ((float*)knT)[tid] = ws[WS_KN + tid];
    __syncthreads();

    // ---- Phase 1: stream y, accumulate DFT partials ----
    const size_t base = (size_t)b * (T_LEN * V_DIM) + (size_t)(g << 2);
    float accre[4][4], accim[4][4];
    #pragma unroll
    for (int j = 0; j < 4; ++j)
        #pragma unroll
        for (int k = 0; k < 4; ++k) { accre[j][k] = 0.f; accim[j][k] = 0.f; }

    for (int i = 0; i < niter; ++i) {
        int t = s + (i << 5);
        float4 yv = *(const float4*)(y + base + (size_t)t * V_DIM);
        uint4 hp = *(const uint4*)(&tabh[t][0]);
        const __half* h = (const __half*)&hp;
        const float cs[4] = {__half2float(h[0]), __half2float(h[1]),
                             __half2float(h[2]), __half2float(h[3])};
        const float sn[4] = {__half2float(h[4]), __half2float(h[5]),
                             __half2float(h[6]), __half2float(h[7])};
        const float yj[4] = {yv.x, yv.y, yv.z, yv.w};
        #pragma unroll
        for (int j = 0; j < 4; ++j)
            #pragma unroll
            for (int k = 0; k < 4; ++k) {
                accre[j][k] = fmaf(yj[j], cs[k], accre[j][k]);
                accim[j][k] = fmaf(yj[j], sn[k], accim[j][k]);
            }
    }

    // ---- Reduce: shuffle over the wave's 4 s-phases, write per-wave partials ----
    #pragma unroll
    for (int j = 0; j < 4; ++j)
        #pragma unroll
        for (int k = 0; k < 4; ++k) {
            float r = accre[j][k], im = accim[j][k];
            r  += __shfl_xor(r, 16, 64);  r  += __shfl_xor(r, 32, 64);
            im += __shfl_xor(im, 16, 64); im += __shfl_xor(im, 32, 64);
            accre[j][k] = r; accim[j][k] = im;
        }
    if (lane < 16) {   // lane == g
        #pragma unroll
        for (int j = 0; j < 4; ++j)
            #pragma unroll
            for (int k = 0; k < 4; ++k) {
                red[lane][w][j * 8 + k]     = accre[j][k];
                red[lane][w][j * 8 + 4 + k] = accim[j][k];
            }
    }
    __syncthreads();

    // ---- Fused fixed-order sum + (scale-1) transform (deterministic) ----
    if (tid < 256) {
        int v = tid >> 2, k = tid & 3;
        int gg = v >> 2, j = v & 3;
        float cr = 0.f, ci = 0.f;
        #pragma unroll
        for (int ww = 0; ww < 8; ++ww) {
            cr += red[gg][ww][j * 8 + k];
            ci += red[gg][ww][j * 8 + 4 + k];
        }
        float sr = ws[WS_SR + k * V_DIM + v];
        float si = ws[WS_SI + k * V_DIM + v];
        const float sc = 2.0f / (float)T_LEN;
        coefT[k][v]     = (cr * sr + ci * si) * sc;   // Re C * 2/T
        coefT[4 + k][v] = (cr * si - ci * sr) * sc;   // Im C * 2/T
    }
    __syncthreads();

    // ---- Phase 2: re-read y (L3-hot), reconstruct + envelope, store ----
    float cre[4][4], cim[4][4];   // [k][j]
    #pragma unroll
    for (int k = 0; k < 4; ++k) {
        float4 r4 = *(const float4*)(&coefT[k][g << 2]);
        float4 i4 = *(const float4*)(&coefT[4 + k][g << 2]);
        cre[k][0] = r4.x; cre[k][1] = r4.y; cre[k][2] = r4.z; cre[k][3] = r4.w;
        cim[k][0] = i4.x; cim[k][1] = i4.y; cim[k][2] = i4.z; cim[k][3] = i4.w;
    }

    const float posScale = 3.0f / 719.0f;
    for (int i = 0; i < niter; ++i) {
        int t = s + (i << 5);
        float4 yv = *(const float4*)(y + base + (size_t)t * V_DIM);
        uint4 hp = *(const uint4*)(&tabh[t][0]);
        const __half* h = (const __half*)&hp;
        const float cs[4] = {__half2float(h[0]), __half2float(h[1]),
                             __half2float(h[2]), __half2float(h[3])};
        const float sn[4] = {__half2float(h[4]), __half2float(h[5]),
                             __half2float(h[6]), __half2float(h[7])};
        float pos = (float)t * posScale;
        int idx = (int)pos; idx = idx > 2 ? 2 : idx;
        float frac = pos - (float)idx;
        float4 e0v = *(const float4*)(&knT[idx][g << 2]);
        float4 e1v = *(const float4*)(&knT[idx + 1][g << 2]);
        const float e0[4] = {e0v.x, e0v.y, e0v.z, e0v.w};
        const float e1[4] = {e1v.x, e1v.y, e1v.z, e1v.w};
        const float yj[4] = {yv.x, yv.y, yv.z, yv.w};
        float oj[4];
        #pragma unroll
        for (int j = 0; j < 4; ++j) {
            float d = 0.f;
            #pragma unroll
            for (int k = 0; k < 4; ++k)
                d = fmaf(cre[k][j], cs[k], fmaf(-cim[k][j], sn[k], d));
            float env = fmaf(e1[j] - e0[j], frac, e0[j]);
            oj[j] = (yj[j] + d) * env;
        }
        float4 o; o.x = oj[0]; o.y = oj[1]; o.z = oj[2]; o.w = oj[3];
        *(float4*)(out + base + (size_t)t * V_DIM) = o;
    }
}

extern "C" void kernel_launch(void* const* d_in, const int* in_sizes, int n_in,
                              void* d_out, int out_size, void* d_ws, size_t ws_size,
                              hipStream_t stream) {
    const float* y         = (const float*)d_in[0];
    const float* a         = (const float*)d_in[1];
    const float* phi       = (const float*)d_in[2];
    const float* env_knots = (const float*)d_in[3];
    const int*   k_bins    = (const int*)d_in[4];
    float* out = (float*)d_out;
    float* ws  = (float*)d_ws;

    int B = in_sizes[0] / (T_LEN * V_DIM);
    int ids = T_LEN * KBINS + V_DIM * KBINS + V_DIM * NKNOTS;
    precompute_kernel<<<(ids + 255) / 256, 256, 0, stream>>>(a, phi, env_knots, k_bins, ws);
    SeasonalEnvelopeAdapter_kernel<<<B, BLOCK, 0, stream>>>(y, ws, out);
}

// Round 9
// 244.639 us; speedup vs baseline: 2.6713x; 2.6713x over previous
//
#include <hip/hip_runtime.h>
#include <math.h>

#define T_LEN   720
#define V_DIM   64
#define KBINS   4
#define NKNOTS  4
#define BLOCK   768     // 12 waves; natural VGPR (no min-waves clamp!)
#define VB      32      // v's per block -> grid = B*2
#define YS      36      // bf16 row stride (72 B, 8B-aligned rows)
#define NW      12
#define TWOPI_720 0.00872664625997164788f

// ws float offsets
#define WS_SR   0       // [4][64] Re(scale)-1
#define WS_SI   256     // [4][64] Im(scale)
#define WS_KN   512     // [4][64] clipped knots

__device__ __forceinline__ unsigned f2bf_rne(float f) {
    unsigned u = __float_as_uint(f);
    return (u + 0x7FFFu + ((u >> 16) & 1u)) >> 16;
}
__device__ __forceinline__ float bf2f(unsigned h) {
    return __uint_as_float(h << 16);
}

// ---- Kernel A: scale transform + knots (tiny) ----
__global__ __launch_bounds__(256) void precompute_kernel(
    const float* __restrict__ a, const float* __restrict__ phi,
    const float* __restrict__ env_knots,
    float* __restrict__ ws)
{
    int id = blockIdx.x * 256 + threadIdx.x;
    if (id < V_DIM * KBINS) {
        int v = id >> 2, k = id & 3;
        float amp = 1.0f + a[id];
        float ph  = tanhf(phi[id]) * 0.25f;
        float sp, cp;
        sincosf(ph, &sp, &cp);
        ws[WS_SR + k * V_DIM + v] = amp * cp - 1.0f;
        ws[WS_SI + k * V_DIM + v] = amp * sp;
    } else if (id < V_DIM * KBINS + V_DIM * NKNOTS) {
        int e = id - V_DIM * KBINS;                  // v*4+n
        int v = e >> 2, n = e & 3;
        ws[WS_KN + n * V_DIM + v] = fminf(fmaxf(env_knots[e], 0.5f), 1.5f);
    }
}

// ---- Kernel B: (b, v-half) blocks; single HBM pass; per-thread trig rotation ----
// LDS 66 KB -> 2 blocks/CU = 24 waves at natural VGPR (<=85). Deterministic reduce.
__global__ __launch_bounds__(BLOCK) void SeasonalEnvelopeAdapter_kernel(
    const float* __restrict__ y,
    const float* __restrict__ ws,
    const int*   __restrict__ k_bins,
    float* __restrict__ out)
{
    __shared__ __align__(16) unsigned short ylds[T_LEN][YS];  // 51,840 B (bf16 y)
    __shared__ float red[8][NW][33];                          // 12,672 B
    __shared__ __align__(16) float coefT[8][VB];              //  1,024 B
    __shared__ __align__(16) float knT[NKNOTS][VB];           //    512 B
    // total 66,048 B

    const int tid  = threadIdx.x;
    const int b    = blockIdx.x >> 1;
    const int q    = blockIdx.x & 1;
    const int vb0  = q * VB;
    const int g    = tid & 7;       // v-group: v = vb0 + 4g
    const int s    = tid >> 3;      // t-phase 0..95 (t = s + 96*i)
    const int lane = tid & 63;
    const int w    = tid >> 6;      // wave 0..11
    const int niter = (s < 48) ? 8 : 7;   // 720 = 96*7 + 48, wave-uniform

    // ---- Phase 0: knots -> LDS (consumed after later barriers) ----
    if (tid < NKNOTS * VB) {
        int n = tid >> 5, vl = tid & 31;
        knT[n][vl] = ws[WS_KN + n * V_DIM + vb0 + vl];
    }

    // ---- Rotation init: exact integer angle reduction, then sincosf ----
    float c0[4], s0[4], Cr[4], Sr[4];
    #pragma unroll
    for (int k = 0; k < 4; ++k) {
        int kb = k_bins[k];
        int m0 = (kb * s) % T_LEN;
        sincosf((float)m0 * TWOPI_720, &s0[k], &c0[k]);
        int m1 = (kb * 96) % T_LEN;
        sincosf((float)m1 * TWOPI_720, &Sr[k], &Cr[k]);
    }

    // ---- Phase 1: stream y once, accumulate DFT, stash bf16 in LDS ----
    const size_t base = (size_t)b * (T_LEN * V_DIM) + (size_t)(vb0 + (g << 2));
    float accre[4][4], accim[4][4];
    #pragma unroll
    for (int j = 0; j < 4; ++j)
        #pragma unroll
        for (int k = 0; k < 4; ++k) { accre[j][k] = 0.f; accim[j][k] = 0.f; }

    {
        float cs[4], sn[4];
        #pragma unroll
        for (int k = 0; k < 4; ++k) { cs[k] = c0[k]; sn[k] = s0[k]; }
        for (int i = 0; i < niter; ++i) {
            int t = s + 96 * i;
            float4 yv = *(const float4*)(y + base + (size_t)t * V_DIM);
            uint2 p;
            p.x = f2bf_rne(yv.x) | (f2bf_rne(yv.y) << 16);
            p.y = f2bf_rne(yv.z) | (f2bf_rne(yv.w) << 16);
            *(uint2*)(&ylds[t][g << 2]) = p;
            const float yj[4] = {yv.x, yv.y, yv.z, yv.w};
            #pragma unroll
            for (int j = 0; j < 4; ++j)
                #pragma unroll
                for (int k = 0; k < 4; ++k) {
                    accre[j][k] = fmaf(yj[j], cs[k], accre[j][k]);
                    accim[j][k] = fmaf(yj[j], sn[k], accim[j][k]);
                }
            #pragma unroll
            for (int k = 0; k < 4; ++k) {   // rotate by stride-96 phase
                float nc = cs[k] * Cr[k] - sn[k] * Sr[k];
                float ns = sn[k] * Cr[k] + cs[k] * Sr[k];
                cs[k] = nc; sn[k] = ns;
            }
        }
    }

    // ---- Reduce: shuffle over same-g lanes (xor 8/16/32), fixed-order LDS tree ----
    #pragma unroll
    for (int j = 0; j < 4; ++j)
        #pragma unroll
        for (int k = 0; k < 4; ++k) {
            float r = accre[j][k], im = accim[j][k];
            r  += __shfl_xor(r, 8, 64);  r  += __shfl_xor(r, 16, 64);  r  += __shfl_xor(r, 32, 64);
            im += __shfl_xor(im, 8, 64); im += __shfl_xor(im, 16, 64); im += __shfl_xor(im, 32, 64);
            accre[j][k] = r; accim[j][k] = im;
        }
    if (lane < 8) {   // lane == g
        #pragma unroll
        for (int j = 0; j < 4; ++j)
            #pragma unroll
            for (int k = 0; k < 4; ++k) {
                red[lane][w][j * 8 + k]     = accre[j][k];
                red[lane][w][j * 8 + 4 + k] = accim[j][k];
            }
    }
    __syncthreads();

    // ---- Fused fixed-order sum + (scale-1) transform (deterministic) ----
    if (tid < VB * KBINS) {          // 128 threads
        int vl = tid >> 2, k = tid & 3;
        int gg = vl >> 2, j = vl & 3;
        float cr = 0.f, ci = 0.f;
        #pragma unroll
        for (int ww = 0; ww < NW; ++ww) {
            cr += red[gg][ww][j * 8 + k];
            ci += red[gg][ww][j * 8 + 4 + k];
        }
        int v = vb0 + vl;
        float sr = ws[WS_SR + k * V_DIM + v];
        float si = ws[WS_SI + k * V_DIM + v];
        const float sc = 2.0f / (float)T_LEN;
        coefT[k][vl]     = (cr * sr + ci * si) * sc;   // Re C * 2/T
        coefT[4 + k][vl] = (cr * si - ci * sr) * sc;   // Im C * 2/T
    }
    __syncthreads();

    // ---- Phase 2: reconstruct from LDS bf16 + envelope, store ----
    float cre[4][4], cim[4][4], knr[4][4];   // [k][j] / [n][j]
    #pragma unroll
    for (int k = 0; k < 4; ++k) {
        float4 r4 = *(const float4*)(&coefT[k][g << 2]);
        float4 i4 = *(const float4*)(&coefT[4 + k][g << 2]);
        cre[k][0] = r4.x; cre[k][1] = r4.y; cre[k][2] = r4.z; cre[k][3] = r4.w;
        cim[k][0] = i4.x; cim[k][1] = i4.y; cim[k][2] = i4.z; cim[k][3] = i4.w;
    }
    #pragma unroll
    for (int n = 0; n < 4; ++n) {
        float4 k4 = *(const float4*)(&knT[n][g << 2]);
        knr[n][0] = k4.x; knr[n][1] = k4.y; knr[n][2] = k4.z; knr[n][3] = k4.w;
    }

    const float posScale = 3.0f / 719.0f;
    {
        float cs[4], sn[4];
        #pragma unroll
        for (int k = 0; k < 4; ++k) { cs[k] = c0[k]; sn[k] = s0[k]; }
        for (int i = 0; i < niter; ++i) {
            int t = s + 96 * i;
            uint2 p = *(const uint2*)(&ylds[t][g << 2]);
            const float yj[4] = { bf2f(p.x & 0xFFFFu), bf2f(p.x >> 16),
                                  bf2f(p.y & 0xFFFFu), bf2f(p.y >> 16) };
            float pos = (float)t * posScale;
            int idx = (int)pos; idx = idx > 2 ? 2 : idx;
            float frac = pos - (float)idx;
            float oj[4];
            #pragma unroll
            for (int j = 0; j < 4; ++j) {
                float d = 0.f;
                #pragma unroll
                for (int k = 0; k < 4; ++k)
                    d = fmaf(cre[k][j], cs[k], fmaf(-cim[k][j], sn[k], d));
                float e0 = (idx == 0) ? knr[0][j] : ((idx == 1) ? knr[1][j] : knr[2][j]);
                float e1 = (idx == 0) ? knr[1][j] : ((idx == 1) ? knr[2][j] : knr[3][j]);
                float env = fmaf(e1 - e0, frac, e0);
                oj[j] = (yj[j] + d) * env;
            }
            float4 o; o.x = oj[0]; o.y = oj[1]; o.z = oj[2]; o.w = oj[3];
            *(float4*)(out + base + (size_t)t * V_DIM) = o;
            #pragma unroll
            for (int k = 0; k < 4; ++k) {
                float nc = cs[k] * Cr[k] - sn[k] * Sr[k];
                float ns = sn[k] * Cr[k] + cs[k] * Sr[k];
                cs[k] = nc; sn[k] = ns;
            }
        }
    }
}

extern "C" void kernel_launch(void* const* d_in, const int* in_sizes, int n_in,
                              void* d_out, int out_size, void* d_ws, size_t ws_size,
                              hipStream_t stream) {
    const float* y         = (const float*)d_in[0];
    const float* a         = (const float*)d_in[1];
    const float* phi       = (const float*)d_in[2];
    const float* env_knots = (const float*)d_in[3];
    const int*   k_bins    = (const int*)d_in[4];
    float* out = (float*)d_out;
    float* ws  = (float*)d_ws;

    int B = in_sizes[0] / (T_LEN * V_DIM);
    precompute_kernel<<<2, 256, 0, stream>>>(a, phi, env_knots, ws);
    SeasonalEnvelopeAdapter_kernel<<<B * 2, BLOCK, 0, stream>>>(y, ws, k_bins, out);
}

// Round 10
// 183.080 us; speedup vs baseline: 3.5695x; 1.3362x over previous
//
#include <hip/hip_runtime.h>
#include <math.h>

#define T_LEN   720
#define V_DIM   64
#define KBINS   4
#define NKNOTS  4
#define BLOCK   768     // 12 waves; 16 v-groups x 48 t-phases; TSLICE uniform 15
#define TSLICE  15
#define NW      12
#define PIPE    4       // rolling prefetch depth

// ws float offsets (kernel A -> kernel B)
#define WS_TAB  0       // [720][8] = {cos k0..3, sin k0..3} per t
#define WS_SR   5760    // [4][64]  Re(scale)-1, [k][v]
#define WS_SI   6016    // [4][64]  Im(scale),   [k][v]
#define WS_KN   6272    // [4][64]  clipped knots, [n][v]

// ---- Kernel A: one-time tables (no transcendentals in kernel B) ----
__global__ __launch_bounds__(256) void precompute_kernel(
    const float* __restrict__ a, const float* __restrict__ phi,
    const float* __restrict__ env_knots, const int* __restrict__ k_bins,
    float* __restrict__ ws)
{
    int id = blockIdx.x * 256 + threadIdx.x;
    if (id < T_LEN * KBINS) {
        int t = id >> 2, k = id & 3;
        int kb = k_bins[k];
        int m  = (kb * t) % T_LEN;                       // exact integer angle reduction
        float th = (float)m * 0.00872664625997164788f;   // 2*pi/720
        float sn, cs;
        sincosf(th, &sn, &cs);
        ws[WS_TAB + t * 8 + k]     = cs;
        ws[WS_TAB + t * 8 + 4 + k] = sn;
    } else if (id < T_LEN * KBINS + V_DIM * KBINS) {
        int e = id - T_LEN * KBINS;                      // v*4+k
        int v = e >> 2, k = e & 3;
        float amp = 1.0f + a[e];
        float ph  = tanhf(phi[e]) * 0.25f;
        float sp, cp;
        sincosf(ph, &sp, &cp);
        ws[WS_SR + k * V_DIM + v] = amp * cp - 1.0f;
        ws[WS_SI + k * V_DIM + v] = amp * sp;
    } else if (id < T_LEN * KBINS + V_DIM * KBINS + V_DIM * NKNOTS) {
        int e = id - T_LEN * KBINS - V_DIM * KBINS;      // v*4+n
        int v = e >> 2, n = e & 3;
        ws[WS_KN + n * V_DIM + v] = fminf(fmaxf(env_knots[e], 0.5f), 1.5f);
    }
}

// ---- Kernel B: one block per b; 4-deep load pipeline; deterministic reduce ----
// LDS 51.5 KB -> 2 blocks/CU (thread cap) = 24 waves at natural VGPR.
__global__ __launch_bounds__(BLOCK) void SeasonalEnvelopeAdapter_kernel(
    const float* __restrict__ y,
    const float* __restrict__ ws,
    float* __restrict__ out)
{
    __shared__ __align__(16) float tab[T_LEN * 8];       // 23,040 B {c0..3,s0..3}/t
    __shared__ float red[16][NW][33];                    // 25,344 B (writer banks 12g%32: 2-way, free)
    __shared__ __align__(16) float coefT[8][V_DIM];      //  2,048 B [k][v] re / [4+k][v] im
    __shared__ __align__(16) float knT[NKNOTS][V_DIM];   //  1,024 B
    // total 51,456 B

    const int tid  = threadIdx.x;
    const int b    = blockIdx.x;
    const int g    = tid & 15;      // v-group: v0 = 4*g -> 256 B/row coalesced
    const int s    = tid >> 4;      // t-phase 0..47; t = 48*i + s (uniform 15 iters)
    const int lane = tid & 63;
    const int w    = tid >> 6;      // wave 0..11

    // ---- Phase 0: ws tables -> LDS ----
    for (int e = tid; e < 1440; e += BLOCK)
        ((float4*)tab)[e] = ((const float4*)(ws + WS_TAB))[e];
    if (tid < NKNOTS * V_DIM) ((float*)knT)[tid] = ws[WS_KN + tid];
    __syncthreads();

    // ---- Phase 1: stream y (4 loads in flight), accumulate DFT partials ----
    const size_t base = (size_t)b * (T_LEN * V_DIM) + (size_t)(g << 2);
    float accre[4][4], accim[4][4];
    #pragma unroll
    for (int j = 0; j < 4; ++j)
        #pragma unroll
        for (int k = 0; k < 4; ++k) { accre[j][k] = 0.f; accim[j][k] = 0.f; }

    {
        float4 yv[PIPE];
        #pragma unroll
        for (int i0 = 0; i0 < PIPE; ++i0)
            yv[i0] = *(const float4*)(y + base + (size_t)(48 * i0 + s) * V_DIM);
        #pragma unroll
        for (int i = 0; i < TSLICE; ++i) {
            int t = 48 * i + s;
            float4 cur = yv[i & (PIPE - 1)];
            if (i + PIPE < TSLICE)
                yv[i & (PIPE - 1)] = *(const float4*)(y + base + (size_t)(48 * (i + PIPE) + s) * V_DIM);
            float4 c4 = *(const float4*)(&tab[t * 8]);
            float4 s4 = *(const float4*)(&tab[t * 8 + 4]);
            const float cs[4] = {c4.x, c4.y, c4.z, c4.w};
            const float sn[4] = {s4.x, s4.y, s4.z, s4.w};
            const float yj[4] = {cur.x, cur.y, cur.z, cur.w};
            #pragma unroll
            for (int j = 0; j < 4; ++j)
                #pragma unroll
                for (int k = 0; k < 4; ++k) {
                    accre[j][k] = fmaf(yj[j], cs[k], accre[j][k]);
                    accim[j][k] = fmaf(yj[j], sn[k], accim[j][k]);
                }
        }
    }

    // ---- Reduce: shuffle over the wave's 4 s-phases, write per-wave partials ----
    #pragma unroll
    for (int j = 0; j < 4; ++j)
        #pragma unroll
        for (int k = 0; k < 4; ++k) {
            float r = accre[j][k], im = accim[j][k];
            r  += __shfl_xor(r, 16, 64);  r  += __shfl_xor(r, 32, 64);
            im += __shfl_xor(im, 16, 64); im += __shfl_xor(im, 32, 64);
            accre[j][k] = r; accim[j][k] = im;
        }
    if (lane < 16) {   // lane == g
        #pragma unroll
        for (int j = 0; j < 4; ++j)
            #pragma unroll
            for (int k = 0; k < 4; ++k) {
                red[lane][w][j * 8 + k]     = accre[j][k];
                red[lane][w][j * 8 + 4 + k] = accim[j][k];
            }
    }
    __syncthreads();

    // ---- Fused fixed-order sum + (scale-1) transform (deterministic) ----
    if (tid < 256) {
        int v = tid >> 2, k = tid & 3;
        int gg = v >> 2, j = v & 3;
        float cr = 0.f, ci = 0.f;
        #pragma unroll
        for (int ww = 0; ww < NW; ++ww) {
            cr += red[gg][ww][j * 8 + k];
            ci += red[gg][ww][j * 8 + 4 + k];
        }
        float sr = ws[WS_SR + k * V_DIM + v];
        float si = ws[WS_SI + k * V_DIM + v];
        const float sc = 2.0f / (float)T_LEN;
        coefT[k][v]     = (cr * sr + ci * si) * sc;   // Re C * 2/T
        coefT[4 + k][v] = (cr * si - ci * sr) * sc;   // Im C * 2/T
    }
    __syncthreads();

    // ---- Phase 2: re-read y (L3-hot, 4 in flight), reconstruct + envelope ----
    float cre[4][4], cim[4][4];   // [k][j]
    #pragma unroll
    for (int k = 0; k < 4; ++k) {
        float4 r4 = *(const float4*)(&coefT[k][g << 2]);
        float4 i4 = *(const float4*)(&coefT[4 + k][g << 2]);
        cre[k][0] = r4.x; cre[k][1] = r4.y; cre[k][2] = r4.z; cre[k][3] = r4.w;
        cim[k][0] = i4.x; cim[k][1] = i4.y; cim[k][2] = i4.z; cim[k][3] = i4.w;
    }

    const float posScale = 3.0f / 719.0f;
    {
        float4 yv[PIPE];
        #pragma unroll
        for (int i0 = 0; i0 < PIPE; ++i0)
            yv[i0] = *(const float4*)(y + base + (size_t)(48 * i0 + s) * V_DIM);
        #pragma unroll
        for (int i = 0; i < TSLICE; ++i) {
            int t = 48 * i + s;
            float4 cur = yv[i & (PIPE - 1)];
            if (i + PIPE < TSLICE)
                yv[i & (PIPE - 1)] = *(const float4*)(y + base + (size_t)(48 * (i + PIPE) + s) * V_DIM);
            float4 c4 = *(const float4*)(&tab[t * 8]);
            float4 s4 = *(const float4*)(&tab[t * 8 + 4]);
            const float cs[4] = {c4.x, c4.y, c4.z, c4.w};
            const float sn[4] = {s4.x, s4.y, s4.z, s4.w};
            float pos = (float)t * posScale;
            int idx = (int)pos; idx = idx > 2 ? 2 : idx;
            float frac = pos - (float)idx;
            float4 e0v = *(const float4*)(&knT[idx][g << 2]);
            float4 e1v = *(const float4*)(&knT[idx + 1][g << 2]);
            const float e0[4] = {e0v.x, e0v.y, e0v.z, e0v.w};
            const float e1[4] = {e1v.x, e1v.y, e1v.z, e1v.w};
            const float yj[4] = {cur.x, cur.y, cur.z, cur.w};
            float oj[4];
            #pragma unroll
            for (int j = 0; j < 4; ++j) {
                float d = 0.f;
                #pragma unroll
                for (int k = 0; k < 4; ++k)
                    d = fmaf(cre[k][j], cs[k], fmaf(-cim[k][j], sn[k], d));
                float env = fmaf(e1[j] - e0[j], frac, e0[j]);
                oj[j] = (yj[j] + d) * env;
            }
            float4 o; o.x = oj[0]; o.y = oj[1]; o.z = oj[2]; o.w = oj[3];
            *(float4*)(out + base + (size_t)t * V_DIM) = o;
        }
    }
}

extern "C" void kernel_launch(void* const* d_in, const int* in_sizes, int n_in,
                              void* d_out, int out_size, void* d_ws, size_t ws_size,
                              hipStream_t stream) {
    const float* y         = (const float*)d_in[0];
    const float* a         = (const float*)d_in[1];
    const float* phi       = (const float*)d_in[2];
    const float* env_knots = (const float*)d_in[3];
    const int*   k_bins    = (const int*)d_in[4];
    float* out = (float*)d_out;
    float* ws  = (float*)d_ws;

    int B = in_sizes[0] / (T_LEN * V_DIM);
    int ids = T_LEN * KBINS + V_DIM * KBINS + V_DIM * NKNOTS;
    precompute_kernel<<<(ids + 255) / 256, 256, 0, stream>>>(a, phi, env_knots, k_bins, ws);
    SeasonalEnvelopeAdapter_kernel<<<B, BLOCK, 0, stream>>>(y, ws, out);
}